// Round 8
// baseline (209.289 us; speedup 1.0000x reference)
//
#include <hip/hip_runtime.h>
#include <hip/hip_bf16.h>

#define BQ 8
#define DIM 512
#define NN 2048
#define MM 2048

typedef __attribute__((ext_vector_type(8))) short short8;
typedef __attribute__((ext_vector_type(4))) float floatx4;

// ws layout:
//   [0, 4MiB) : partials [b][slot16][n] float4 {l, o0, o1, o2}  (16 slots/b)

static __device__ __forceinline__ unsigned short f2bf(float x) {
    __hip_bfloat16 h = __float2bfloat16(x);
    return *(unsigned short*)&h;
}

// ---------------- fused transpose+cast+MFMA attention ----------------
// R21: transpose_cast kernel DELETED (~35-40us of pure BW + a launch gap).
// Evidence: attn is invariant at ~47.5us across R13/R18/R20 variants
// (LDS-read count, drain count, pipelining all falsified); the remaining
// pipeline time is transpose + gaps. Here attn stages DIRECTLY from the
// fp32 [d][n] source: per 8-d chunk, 8 coalesced b32 loads (lane <-> n,
// 256B/row), pack to bf16 in regs (RNE, same as old transpose), one
// ds_write_b128 into the transposed LDS row at XOR-swizzled phys chunk
// g^(row&7) -- reg-staged writes allow the swizzle (m104); read side is
// bit-identical to harness-verified R18 (phys (ks*4+quad)^(lm&7), rows
// wn+i*16+lm; 0 conflicts measured R13/R18). Geometry = R18: 256n x 128m
// block, 4 waves x (64n x 128m, acc[4][8]), BK=64, 48KB LDS, grid
// 8x16x8=1024. Write-conflict check: 64 lanes write 64 rows (stride
// 128B) at chunk j^(lane&7): per 16-lane phase 8 chunks x 2 rows = full
// 32-bank cover, 2-way (free). B: lanes 0-31 chunk 2j2, 32-63 chunk
// 2j2+1, same structure. HBM: fp32 panels re-read from L2/L3 (128MB
// total, L3-resident) instead of bf16 from HBM.
__global__ __launch_bounds__(256, 2) void attn_fused_kernel(
    const float* __restrict__ src_emb,   // [B, D, N]
    const float* __restrict__ tgt_emb,   // [B, D, M]
    const float* __restrict__ tgt,       // [B, 3, M]
    float* __restrict__ part)            // [b][slot16][n] float4
{
    const int nt = blockIdx.x;      // 0..7   n tile of 256
    const int qt = blockIdx.y;      // 0..15  m tile of 128
    const int b  = blockIdx.z;      // 0..7
    const int t  = threadIdx.x;     // 0..255
    const int wave = t >> 6;        // 0..3
    const int lane = t & 63;
    const int lm   = lane & 15;
    const int quad = lane >> 4;
    const int wn   = wave * 64;     // wave's n offset in the 256 tile

    // A 256 rows x 64 d x 2B = 32KB; B 128 rows = 16KB (bf16, swizzled)
    __shared__ short As[256 * 64];
    __shared__ short Bs[128 * 64];

    const float* Ab = src_emb + (size_t)b * DIM * NN + nt * 256;
    const int m0 = qt * 128;
    const float* Bb = tgt_emb + (size_t)b * DIM * MM + m0;
    const float* Tb = tgt + (size_t)b * 3 * MM;

    const float SCALE = 0.044194173824159216f * 1.4426950408889634f;

    // staging lane roles
    const int na  = wave * 64 + lane;        // A: n-row this lane owns (0..255)
    const int mb  = wave * 32 + (lane & 31); // B: m-row this lane owns (0..127)
    const int bch = lane >> 5;               // B: which of 2 chunks this half-wave does

    floatx4 acc[4][8];
    #pragma unroll
    for (int i = 0; i < 4; i++)
        #pragma unroll
        for (int j = 0; j < 8; j++)
            acc[i][j] = (floatx4){0.f, 0.f, 0.f, 0.f};

    #pragma unroll
    for (int kt = 0; kt < 8; kt++) {     // d chunks of 64 elements
        // ---- A staging: 8 d-subchunks of 8; lane covers its n-row ----
        #pragma unroll
        for (int j = 0; j < 8; j++) {
            float v[8];
            #pragma unroll
            for (int jj = 0; jj < 8; jj++)
                v[jj] = Ab[(size_t)(kt * 64 + j * 8 + jj) * NN + na];
            unsigned int p[4];
            #pragma unroll
            for (int jj = 0; jj < 4; jj++)
                p[jj] = ((unsigned)f2bf(v[2 * jj + 1]) << 16) | (unsigned)f2bf(v[2 * jj]);
            const int pc = (j ^ (na & 7)) * 8;   // phys chunk = g ^ (row&7)
            uint4 w; w.x = p[0]; w.y = p[1]; w.z = p[2]; w.w = p[3];
            *(uint4*)&As[na * 64 + pc] = w;
        }
        // ---- B staging: half-wave per chunk, 4 passes x 2 chunks ----
        #pragma unroll
        for (int j2 = 0; j2 < 4; j2++) {
            const int j = j2 * 2 + bch;
            float v[8];
            #pragma unroll
            for (int jj = 0; jj < 8; jj++)
                v[jj] = Bb[(size_t)(kt * 64 + j * 8 + jj) * MM + mb];
            unsigned int p[4];
            #pragma unroll
            for (int jj = 0; jj < 4; jj++)
                p[jj] = ((unsigned)f2bf(v[2 * jj + 1]) << 16) | (unsigned)f2bf(v[2 * jj]);
            const int pc = (j ^ (mb & 7)) * 8;
            uint4 w; w.x = p[0]; w.y = p[1]; w.z = p[2]; w.w = p[3];
            *(uint4*)&Bs[mb * 64 + pc] = w;
        }
        __syncthreads();                 // drains ds_writes for all waves

        // ---- fragment reads + MFMA: verbatim R18 (0-conflict verified) ----
        #pragma unroll
        for (int ks = 0; ks < 2; ks++) {
            const int pc = (((ks * 4 + quad) ^ (lane & 7)) * 8);
            short8 af[4];
            #pragma unroll
            for (int i = 0; i < 4; i++)
                af[i] = *(const short8*)&As[(wn + i * 16 + lm) * 64 + pc];
            #pragma unroll
            for (int j = 0; j < 8; j++) {
                short8 bf = *(const short8*)&Bs[(j * 16 + lm) * 64 + pc];
                #pragma unroll
                for (int i = 0; i < 4; i++)
                    acc[i][j] = __builtin_amdgcn_mfma_f32_16x16x32_bf16(af[i], bf, acc[i][j], 0, 0, 0);
            }
        }
        __syncthreads();
    }

    // V rows from global (L2-hot)
    float v0[8], v1[8], v2[8];
    #pragma unroll
    for (int j = 0; j < 8; j++) {
        int vc = m0 + j * 16 + lm;
        v0[j] = Tb[vc];
        v1[j] = Tb[MM + vc];
        v2[j] = Tb[2 * MM + vc];
    }

    const size_t slot = (size_t)(b * 16 + qt) * NN;
    // C/D layout (m89/m91): col = lane&15 (m), row = quad*4+reg (n)
    #pragma unroll
    for (int i = 0; i < 4; i++) {
        float l4[4] = {0,0,0,0};
        float o0[4] = {0,0,0,0};
        float o1[4] = {0,0,0,0};
        float o2[4] = {0,0,0,0};
        #pragma unroll
        for (int j = 0; j < 8; j++) {
            #pragma unroll
            for (int r = 0; r < 4; r++) {
                float e = __builtin_amdgcn_exp2f(acc[i][j][r] * SCALE);
                l4[r] += e;
                o0[r] += e * v0[j];
                o1[r] += e * v1[j];
                o2[r] += e * v2[j];
            }
        }
        #pragma unroll
        for (int m = 1; m <= 8; m <<= 1) {
            #pragma unroll
            for (int r = 0; r < 4; r++) {
                l4[r] += __shfl_xor(l4[r], m);
                o0[r] += __shfl_xor(o0[r], m);
                o1[r] += __shfl_xor(o1[r], m);
                o2[r] += __shfl_xor(o2[r], m);
            }
        }
        if (lm == 0) {
            #pragma unroll
            for (int r = 0; r < 4; r++) {
                int n = nt * 256 + wn + i * 16 + quad * 4 + r;
                ((float4*)part)[slot + n] = make_float4(l4[r], o0[r], o1[r], o2[r]);
            }
        }
    }
}

// ---------------- fused finish: reduce partials + Procrustes ----------------
// (verified in R20: merges reduce1 + procrustes, 8 blocks x 256 thr)
__global__ __launch_bounds__(256) void finish_kernel(
    const float* __restrict__ part,
    const float* __restrict__ src,       // [B,3,N]
    const float* __restrict__ tgt,       // [B,3,M]
    float* __restrict__ out)             // [72 R][24 t]
{
    const int b = blockIdx.x;
    const int t = threadIdx.x;           // 0..255
    const int wave = t >> 6;
    const int lane = t & 63;

    const float4* w4 = (const float4*)part;
    const float* S = src + (size_t)b * 3 * NN;
    const float* T = tgt + (size_t)b * 3 * MM;

    float vals[18];
    #pragma unroll
    for (int c = 0; c < 18; c++) vals[c] = 0.f;

    for (int k = 0; k < 8; k++) {
        const int n = t + k * 256;
        float l = 0.f, y0 = 0.f, y1 = 0.f, y2 = 0.f;
        #pragma unroll
        for (int q = 0; q < 16; q++) {
            float4 p = w4[(size_t)(b * 16 + q) * NN + n];
            l += p.x; y0 += p.y; y1 += p.z; y2 += p.w;
        }
        float inv = 1.0f / l;
        float c0 = y0 * inv, c1 = y1 * inv, c2 = y2 * inv;
        float s0 = S[n], s1 = S[NN + n], s2 = S[2 * NN + n];

        vals[0] += s0;  vals[1] += s1;  vals[2] += s2;
        vals[3] += c0;  vals[4] += c1;  vals[5] += c2;
        vals[6] += T[n]; vals[7] += T[MM + n]; vals[8] += T[2 * MM + n];
        vals[9]  += s0 * c0; vals[10] += s0 * c1; vals[11] += s0 * c2;
        vals[12] += s1 * c0; vals[13] += s1 * c1; vals[14] += s1 * c2;
        vals[15] += s2 * c0; vals[16] += s2 * c1; vals[17] += s2 * c2;
    }

    #pragma unroll
    for (int m = 1; m <= 32; m <<= 1)
        #pragma unroll
        for (int c = 0; c < 18; c++)
            vals[c] += __shfl_xor(vals[c], m);

    __shared__ float wsum[4][18];
    if (lane == 0)
        #pragma unroll
        for (int c = 0; c < 18; c++) wsum[wave][c] = vals[c];
    __syncthreads();

    if (t == 0) {
        float res[18];
        #pragma unroll
        for (int c = 0; c < 18; c++)
            res[c] = wsum[0][c] + wsum[1][c] + wsum[2][c] + wsum[3][c];

        const float invN = 1.0f / (float)NN;
        float mus[3], muc[3], mut[3], H[3][3];
        for (int i = 0; i < 3; i++) {
            mus[i] = res[i] * invN;
            muc[i] = res[3 + i] * invN;
            mut[i] = res[6 + i] * invN;
        }
        for (int i = 0; i < 3; i++)
            for (int j = 0; j < 3; j++)
                H[i][j] = res[9 + i * 3 + j] - (float)NN * mus[i] * muc[j];

        float A[3][3];
        for (int i = 0; i < 3; i++)
            for (int j = 0; j < 3; j++)
                A[i][j] = H[0][i] * H[0][j] + H[1][i] * H[1][j] + H[2][i] * H[2][j];

        float V[3][3] = {{1,0,0},{0,1,0},{0,0,1}};
        for (int sweep = 0; sweep < 6; sweep++) {
            for (int pi = 0; pi < 3; pi++) {
                int p = (pi < 2) ? 0 : 1;
                int q = (pi == 0) ? 1 : 2;
                float apq = A[p][q];
                if (fabsf(apq) < 1e-30f) continue;
                float tau = (A[q][q] - A[p][p]) / (2.0f * apq);
                float tt = (tau >= 0.0f) ? 1.0f / (tau + sqrtf(1.0f + tau * tau))
                                         : -1.0f / (-tau + sqrtf(1.0f + tau * tau));
                float c = 1.0f / sqrtf(1.0f + tt * tt);
                float s = tt * c;
                for (int k = 0; k < 3; k++) {
                    float akp = A[k][p], akq = A[k][q];
                    A[k][p] = c * akp - s * akq;
                    A[k][q] = s * akp + c * akq;
                }
                for (int k = 0; k < 3; k++) {
                    float apk = A[p][k], aqk = A[q][k];
                    A[p][k] = c * apk - s * aqk;
                    A[q][k] = s * apk + c * aqk;
                }
                for (int k = 0; k < 3; k++) {
                    float vkp = V[k][p], vkq = V[k][q];
                    V[k][p] = c * vkp - s * vkq;
                    V[k][q] = s * vkp + c * vkq;
                }
            }
        }

        float lam[3] = {A[0][0], A[1][1], A[2][2]};
        int idx[3] = {0, 1, 2};
        for (int a = 0; a < 2; a++)
            for (int bb = 0; bb < 2 - a; bb++)
                if (lam[idx[bb]] < lam[idx[bb + 1]]) { int tmp = idx[bb]; idx[bb] = idx[bb + 1]; idx[bb + 1] = tmp; }

        float Vc[3][3], U[3][3];
        for (int c = 0; c < 3; c++) {
            float sv = sqrtf(fmaxf(lam[idx[c]], 0.0f));
            float isv = 1.0f / fmaxf(sv, 1e-20f);
            for (int r = 0; r < 3; r++) {
                Vc[r][c] = V[r][idx[c]];
                U[r][c] = (H[r][0] * V[0][idx[c]] + H[r][1] * V[1][idx[c]] + H[r][2] * V[2][idx[c]]) * isv;
            }
        }

        {
            float nrm = rsqrtf(U[0][0]*U[0][0] + U[1][0]*U[1][0] + U[2][0]*U[2][0]);
            for (int r = 0; r < 3; r++) U[r][0] *= nrm;
            float d01 = U[0][0]*U[0][1] + U[1][0]*U[1][1] + U[2][0]*U[2][1];
            for (int r = 0; r < 3; r++) U[r][1] -= d01 * U[r][0];
            nrm = rsqrtf(U[0][1]*U[0][1] + U[1][1]*U[1][1] + U[2][1]*U[2][1]);
            for (int r = 0; r < 3; r++) U[r][1] *= nrm;
            float d02 = U[0][0]*U[0][2] + U[1][0]*U[1][2] + U[2][0]*U[2][2];
            float d12 = U[0][1]*U[0][2] + U[1][1]*U[1][2] + U[2][1]*U[2][2];
            for (int r = 0; r < 3; r++) U[r][2] -= d02 * U[r][0] + d12 * U[r][1];
            nrm = rsqrtf(U[0][2]*U[0][2] + U[1][2]*U[1][2] + U[2][2]*U[2][2]);
            for (int r = 0; r < 3; r++) U[r][2] *= nrm;
        }

        float det = H[0][0]*(H[1][1]*H[2][2] - H[1][2]*H[2][1])
                  - H[0][1]*(H[1][0]*H[2][2] - H[1][2]*H[2][0])
                  + H[0][2]*(H[1][0]*H[2][1] - H[1][1]*H[2][0]);
        float sgn = (det < 0.0f) ? -1.0f : 1.0f;

        float R[3][3];
        for (int i = 0; i < 3; i++)
            for (int j = 0; j < 3; j++)
                R[i][j] = Vc[i][0]*U[j][0] + Vc[i][1]*U[j][1] + sgn * Vc[i][2]*U[j][2];

        for (int i = 0; i < 3; i++)
            for (int j = 0; j < 3; j++)
                out[b * 9 + i * 3 + j] = R[i][j];
        for (int i = 0; i < 3; i++)
            out[BQ * 9 + b * 3 + i] = mut[i] - (R[i][0]*mus[0] + R[i][1]*mus[1] + R[i][2]*mus[2]);
    }
}

extern "C" void kernel_launch(void* const* d_in, const int* in_sizes, int n_in,
                              void* d_out, int out_size, void* d_ws, size_t ws_size,
                              hipStream_t stream) {
    const float* src_emb = (const float*)d_in[0];
    const float* tgt_emb = (const float*)d_in[1];
    const float* src     = (const float*)d_in[2];
    const float* tgt     = (const float*)d_in[3];
    float* out = (float*)d_out;

    float* part = (float*)d_ws;          // 4 MiB

    dim3 gridA(NN / 256, MM / 128, BQ);  // 8 x 16 x 8 = 1024 blocks
    attn_fused_kernel<<<gridA, 256, 0, stream>>>(src_emb, tgt_emb, tgt, part);

    finish_kernel<<<BQ, 256, 0, stream>>>(part, src, tgt, out);
}

// Round 9
// 158.153 us; speedup vs baseline: 1.3233x; 1.3233x over previous
//
#include <hip/hip_runtime.h>
#include <hip/hip_bf16.h>

#define BQ 8
#define DIM 512
#define NN 2048
#define MM 2048

typedef __attribute__((ext_vector_type(8))) short short8;
typedef __attribute__((ext_vector_type(8))) unsigned short ushort8;
typedef __attribute__((ext_vector_type(4))) float floatx4;

// async global->LDS, 16B per lane, dest = wave-uniform base + lane*16.
#define GLOAD_LDS(gp, lp) \
    __builtin_amdgcn_global_load_lds( \
        (const __attribute__((address_space(1))) void*)(gp), \
        (__attribute__((address_space(3))) void*)(lp), 16, 0, 0)

// ws layout:
//   [0, 4MiB)        : partials [b][slot16][n] float4 {l, o0, o1, o2}  (16 slots/b)
//   [4MiB, 20MiB)    : Abf  [B][N][D] bf16  (transposed src_embedding)
//   [20MiB, 36MiB)   : Bbf  [B][M][D] bf16  (transposed tgt_embedding)
//   [36MiB, +9KiB)   : red  [b][chunk][18]  stage-1 reduction sums

static __device__ __forceinline__ unsigned short f2bf(float x) {
    __hip_bfloat16 h = __float2bfloat16(x);
    return *(unsigned short*)&h;
}

// ---------------- transpose + fp32->bf16 cast (R22 rebuild) ----------------
// R21's ledger algebra located ~58us here (T+X=71.6 from R20-R21; F>=20 =>
// X<=17 => T>=55): the old 64x64 tile did 256B-chunk reads and 128B-chunk
// writes (~1.7TB/s achieved). This version: 256n x 128d tiles, 512 blocks,
// 64KB bf16 LDS, 2 blocks/CU.
//   reads : one FULL 1KB wave-contiguous float4 row per issue (256n x 4B)
//   writes: 256B contiguous chunks (16 lanes x ushort8, 128 d per out-row)
//   cast  : fp32->bf16 in regs BEFORE LDS (halves LDS bytes, enables 8B units)
// LDS swizzle (conflict-checked): element (d,n) at shorts
//   d*256 + (((n>>2) ^ f(d))<<2) + (n&3),  f(d) = ((d&7)<<3) ^ (d>>3)
// store: per row, 64 lanes hit 64 DISTINCT 8B units -> 4 lanes/bank = b64
// minimum (free). gather: per wave, unit = C ^ u (16 distinct) x 2 words,
// 2 lanes/word-bank -> free (m136: 2-way is 1.02x).
__global__ __launch_bounds__(256, 2) void transpose_cast_kernel(
    const float* __restrict__ src_emb,   // [B, D, N]
    const float* __restrict__ tgt_emb,   // [B, D, M]
    __hip_bfloat16* __restrict__ Abf,    // [B, N, D]
    __hip_bfloat16* __restrict__ Bbf)    // [B, M, D]
{
    const int n0 = blockIdx.x * 256;
    const int d0 = blockIdx.y * 128;
    const int b  = blockIdx.z & 7;
    const int which = blockIdx.z >> 3;

    const float* in = (which == 0 ? src_emb : tgt_emb) + (size_t)b * DIM * NN;
    __hip_bfloat16* out = (which == 0 ? Abf : Bbf) + (size_t)b * NN * DIM;

    __shared__ unsigned short tl[128 * 256];   // 64KB

    const int t = threadIdx.x;
    const int w = t >> 6;
    const int lane = t & 63;

    // ---- stage: each wave reads 32 full 1KB rows (d = it*4 + w) ----
    #pragma unroll 8
    for (int it = 0; it < 32; it++) {
        const int dl = it * 4 + w;
        float4 v = *(const float4*)&in[(size_t)(d0 + dl) * NN + n0 + lane * 4];
        unsigned int p0 = ((unsigned)f2bf(v.y) << 16) | (unsigned)f2bf(v.x);
        unsigned int p1 = ((unsigned)f2bf(v.w) << 16) | (unsigned)f2bf(v.z);
        const int f = ((dl & 7) << 3) ^ (dl >> 3);
        *(uint2*)&tl[dl * 256 + ((lane ^ f) << 2)] = make_uint2(p0, p1);
    }
    __syncthreads();

    // ---- write: 16 passes x 16 out-rows; lane u gathers d = u*8..u*8+7 ----
    const int u = t & 15;
    #pragma unroll 4
    for (int pass = 0; pass < 16; pass++) {
        const int rn = (t >> 4) + pass * 16;
        ushort8 o;
        #pragma unroll
        for (int j = 0; j < 8; j++) {
            const int d = u * 8 + j;
            const int f = ((d & 7) << 3) ^ (d >> 3);   // = (j<<3) ^ u
            o[j] = tl[d * 256 + (((rn >> 2) ^ f) << 2) + (rn & 3)];
        }
        *(ushort8*)&out[(size_t)(n0 + rn) * DIM + d0 + u * 8] = o;
    }
}

// ---------------- MFMA attention + soft correspondence ----------------
// R18 (harness-verified, 47.7us): simple schedule (stage -> __syncthreads ->
// read+MFMA -> __syncthreads), single 48KB buffer, 256n x 128m block tile,
// 4 waves x (64n x 128m, acc[4][8]), grid 1024. Kept verbatim: R13==R18
// falsified LDS-read-count model; R14-R17 falsified deep pipelines; R20
// falsified drain-count. attn is structurally ~47.5us in this regime.
// Swizzle (R9, 0 conflicts measured): LDS row's phys chunk c holds global
// chunk c^(row&7) (row bases 8-aligned); read phys ((ks*4+quad)^(lane&7)).
__global__ __launch_bounds__(256, 2) void attn_mfma_kernel(
    const __hip_bfloat16* __restrict__ Abf,  // [B, N, D]
    const __hip_bfloat16* __restrict__ Bbf,  // [B, M, D]
    const float* __restrict__ tgt,           // [B, 3, M]
    float* __restrict__ part)                // [b][slot16][n] float4
{
    const int nt = blockIdx.x;      // 0..7   n tile of 256
    const int qt = blockIdx.y;      // 0..15  m tile of 128
    const int b  = blockIdx.z;      // 0..7
    const int t  = threadIdx.x;     // 0..255
    const int wave = t >> 6;        // 0..3
    const int lane = t & 63;
    const int lm   = lane & 15;
    const int quad = lane >> 4;
    const int wn   = wave * 64;     // wave's n offset in the 256 tile

    // single-buffered: A 256 rows x 8 chunks x 16B = 32KB; B 128 rows = 16KB
    __shared__ short As[256 * 64];
    __shared__ short Bs[128 * 64];

    const __hip_bfloat16* Abase = Abf + ((size_t)(b * NN + nt * 256)) * DIM;
    const int m0 = qt * 128;
    const __hip_bfloat16* Bbase = Bbf + ((size_t)(b * MM + m0)) * DIM;
    const float* Tb = tgt + (size_t)b * 3 * MM;

    const float SCALE = 0.044194173824159216f * 1.4426950408889634f;

    // staging geometry: lane = r8*8 + c8 covers row (+r8, +8/issue), phys
    // chunk c8, fetching global chunk c8^r8 (row bases are 8-aligned)
    const int r8 = lane >> 3;
    const int c8 = lane & 7;
    const int cc = c8 ^ r8;
    // A: wave stages 64 rows at wave*64 (8 issues); B: 32 rows at wave*32 (4)
    const __hip_bfloat16* gA = Abase + (size_t)(wave * 64 + r8) * DIM + cc * 8;
    const __hip_bfloat16* gB = Bbase + (size_t)(wave * 32 + r8) * DIM + cc * 8;
    short* lA = &As[wave * 64 * 64];
    short* lB = &Bs[wave * 32 * 64];

    floatx4 acc[4][8];
    #pragma unroll
    for (int i = 0; i < 4; i++)
        #pragma unroll
        for (int j = 0; j < 8; j++)
            acc[i][j] = (floatx4){0.f, 0.f, 0.f, 0.f};

    #pragma unroll
    for (int kt = 0; kt < 8; kt++) {     // d chunks of 64 elements
        #pragma unroll
        for (int i = 0; i < 8; i++)      // 8 A-rows per issue x8 = 64 rows
            GLOAD_LDS(gA + kt * 64 + (size_t)i * 8 * DIM, lA + i * 512);
        #pragma unroll
        for (int i = 0; i < 4; i++)      // 8 B-rows per issue x4 = 32 rows
            GLOAD_LDS(gB + kt * 64 + (size_t)i * 8 * DIM, lB + i * 512);
        __syncthreads();                 // implicit vmcnt(0)+lgkmcnt(0) drain

        #pragma unroll
        for (int ks = 0; ks < 2; ks++) {
            const int pc = (((ks * 4 + quad) ^ (lane & 7)) * 8);
            short8 af[4];
            #pragma unroll
            for (int i = 0; i < 4; i++)
                af[i] = *(const short8*)&As[(wn + i * 16 + lm) * 64 + pc];
            #pragma unroll
            for (int j = 0; j < 8; j++) {
                short8 bf = *(const short8*)&Bs[(j * 16 + lm) * 64 + pc];
                #pragma unroll
                for (int i = 0; i < 4; i++)
                    acc[i][j] = __builtin_amdgcn_mfma_f32_16x16x32_bf16(af[i], bf, acc[i][j], 0, 0, 0);
            }
        }
        __syncthreads();
    }

    // V rows from global (L2-hot)
    float v0[8], v1[8], v2[8];
    #pragma unroll
    for (int j = 0; j < 8; j++) {
        int vc = m0 + j * 16 + lm;
        v0[j] = Tb[vc];
        v1[j] = Tb[MM + vc];
        v2[j] = Tb[2 * MM + vc];
    }

    const size_t slot = (size_t)(b * 16 + qt) * NN;
    // C/D layout (m89/m91): col = lane&15 (m), row = quad*4+reg (n)
    #pragma unroll
    for (int i = 0; i < 4; i++) {
        float l4[4] = {0,0,0,0};
        float o0[4] = {0,0,0,0};
        float o1[4] = {0,0,0,0};
        float o2[4] = {0,0,0,0};
        #pragma unroll
        for (int j = 0; j < 8; j++) {
            #pragma unroll
            for (int r = 0; r < 4; r++) {
                float e = __builtin_amdgcn_exp2f(acc[i][j][r] * SCALE);
                l4[r] += e;
                o0[r] += e * v0[j];
                o1[r] += e * v1[j];
                o2[r] += e * v2[j];
            }
        }
        #pragma unroll
        for (int m = 1; m <= 8; m <<= 1) {
            #pragma unroll
            for (int r = 0; r < 4; r++) {
                l4[r] += __shfl_xor(l4[r], m);
                o0[r] += __shfl_xor(o0[r], m);
                o1[r] += __shfl_xor(o1[r], m);
                o2[r] += __shfl_xor(o2[r], m);
            }
        }
        if (lm == 0) {
            #pragma unroll
            for (int r = 0; r < 4; r++) {
                int n = nt * 256 + wn + i * 16 + quad * 4 + r;
                ((float4*)part)[slot + n] = make_float4(l4[r], o0[r], o1[r], o2[r]);
            }
        }
    }
}

// ---------------- stage-1 reduce: 128 blocks ----------------
// (kept: R21's ledger shows reduce1+procrustes ~8.5us total vs the 8-block
// fused finish at ~29us -- parallelism beats launch-count here)
__global__ __launch_bounds__(128) void reduce1_kernel(
    const float* __restrict__ part,
    const float* __restrict__ src,       // [B,3,N]
    const float* __restrict__ tgt,       // [B,3,M]
    float* __restrict__ red)             // [b][chunk][18]
{
    const int chunk = blockIdx.x;        // 0..15
    const int b     = blockIdx.y;        // 0..7
    const int t     = threadIdx.x;       // 0..127
    const int n     = chunk * 128 + t;

    const float4* w4 = (const float4*)part;
    const float* S = src + (size_t)b * 3 * NN;
    const float* T = tgt + (size_t)b * 3 * MM;

    float l = 0.f, y0 = 0.f, y1 = 0.f, y2 = 0.f;
    #pragma unroll
    for (int q = 0; q < 16; q++) {
        float4 p = w4[(size_t)(b * 16 + q) * NN + n];
        l += p.x; y0 += p.y; y1 += p.z; y2 += p.w;
    }
    float inv = 1.0f / l;
    float c0 = y0 * inv, c1 = y1 * inv, c2 = y2 * inv;
    float s0 = S[n], s1 = S[NN + n], s2 = S[2 * NN + n];

    float vals[18];
    vals[0] = s0;  vals[1] = s1;  vals[2] = s2;
    vals[3] = c0;  vals[4] = c1;  vals[5] = c2;
    vals[6] = T[n]; vals[7] = T[MM + n]; vals[8] = T[2 * MM + n];
    vals[9]  = s0 * c0; vals[10] = s0 * c1; vals[11] = s0 * c2;
    vals[12] = s1 * c0; vals[13] = s1 * c1; vals[14] = s1 * c2;
    vals[15] = s2 * c0; vals[16] = s2 * c1; vals[17] = s2 * c2;

    #pragma unroll
    for (int m = 1; m <= 32; m <<= 1)
        #pragma unroll
        for (int c = 0; c < 18; c++)
            vals[c] += __shfl_xor(vals[c], m);

    __shared__ float w0[18];
    if (t == 64)
        #pragma unroll
        for (int c = 0; c < 18; c++) w0[c] = vals[c];
    __syncthreads();
    if (t == 0)
        #pragma unroll
        for (int c = 0; c < 18; c++)
            red[(size_t)(b * 16 + chunk) * 18 + c] = vals[c] + w0[c];
}

// ---------------- stage-2: combine 16 chunk-sums, Procrustes ----------------
__global__ __launch_bounds__(64) void procrustes_kernel(
    const float* __restrict__ red,       // [b][chunk][18]
    float* __restrict__ out)             // [72 R][24 t]
{
    const int b = blockIdx.x;
    const int t = threadIdx.x;

    __shared__ float res[18];
    if (t < 18) {
        float a = 0.f;
        #pragma unroll
        for (int q = 0; q < 16; q++)
            a += red[(size_t)(b * 16 + q) * 18 + t];
        res[t] = a;
    }
    __syncthreads();

    if (t == 0) {
        const float invN = 1.0f / (float)NN;
        float mus[3], muc[3], mut[3], H[3][3];
        for (int i = 0; i < 3; i++) {
            mus[i] = res[i] * invN;
            muc[i] = res[3 + i] * invN;
            mut[i] = res[6 + i] * invN;
        }
        for (int i = 0; i < 3; i++)
            for (int j = 0; j < 3; j++)
                H[i][j] = res[9 + i * 3 + j] - (float)NN * mus[i] * muc[j];

        float A[3][3];
        for (int i = 0; i < 3; i++)
            for (int j = 0; j < 3; j++)
                A[i][j] = H[0][i] * H[0][j] + H[1][i] * H[1][j] + H[2][i] * H[2][j];

        float V[3][3] = {{1,0,0},{0,1,0},{0,0,1}};
        for (int sweep = 0; sweep < 6; sweep++) {
            for (int pi = 0; pi < 3; pi++) {
                int p = (pi < 2) ? 0 : 1;
                int q = (pi == 0) ? 1 : 2;
                float apq = A[p][q];
                if (fabsf(apq) < 1e-30f) continue;
                float tau = (A[q][q] - A[p][p]) / (2.0f * apq);
                float tt = (tau >= 0.0f) ? 1.0f / (tau + sqrtf(1.0f + tau * tau))
                                         : -1.0f / (-tau + sqrtf(1.0f + tau * tau));
                float c = 1.0f / sqrtf(1.0f + tt * tt);
                float s = tt * c;
                for (int k = 0; k < 3; k++) {
                    float akp = A[k][p], akq = A[k][q];
                    A[k][p] = c * akp - s * akq;
                    A[k][q] = s * akp + c * akq;
                }
                for (int k = 0; k < 3; k++) {
                    float apk = A[p][k], aqk = A[q][k];
                    A[p][k] = c * apk - s * aqk;
                    A[q][k] = s * apk + c * aqk;
                }
                for (int k = 0; k < 3; k++) {
                    float vkp = V[k][p], vkq = V[k][q];
                    V[k][p] = c * vkp - s * vkq;
                    V[k][q] = s * vkp + c * vkq;
                }
            }
        }

        float lam[3] = {A[0][0], A[1][1], A[2][2]};
        int idx[3] = {0, 1, 2};
        for (int a = 0; a < 2; a++)
            for (int bb = 0; bb < 2 - a; bb++)
                if (lam[idx[bb]] < lam[idx[bb + 1]]) { int tmp = idx[bb]; idx[bb] = idx[bb + 1]; idx[bb + 1] = tmp; }

        float Vc[3][3], U[3][3];
        for (int c = 0; c < 3; c++) {
            float sv = sqrtf(fmaxf(lam[idx[c]], 0.0f));
            float isv = 1.0f / fmaxf(sv, 1e-20f);
            for (int r = 0; r < 3; r++) {
                Vc[r][c] = V[r][idx[c]];
                U[r][c] = (H[r][0] * V[0][idx[c]] + H[r][1] * V[1][idx[c]] + H[r][2] * V[2][idx[c]]) * isv;
            }
        }

        {
            float nrm = rsqrtf(U[0][0]*U[0][0] + U[1][0]*U[1][0] + U[2][0]*U[2][0]);
            for (int r = 0; r < 3; r++) U[r][0] *= nrm;
            float d01 = U[0][0]*U[0][1] + U[1][0]*U[1][1] + U[2][0]*U[2][1];
            for (int r = 0; r < 3; r++) U[r][1] -= d01 * U[r][0];
            nrm = rsqrtf(U[0][1]*U[0][1] + U[1][1]*U[1][1] + U[2][1]*U[2][1]);
            for (int r = 0; r < 3; r++) U[r][1] *= nrm;
            float d02 = U[0][0]*U[0][2] + U[1][0]*U[1][2] + U[2][0]*U[2][2];
            float d12 = U[0][1]*U[0][2] + U[1][1]*U[1][2] + U[2][1]*U[2][2];
            for (int r = 0; r < 3; r++) U[r][2] -= d02 * U[r][0] + d12 * U[r][1];
            nrm = rsqrtf(U[0][2]*U[0][2] + U[1][2]*U[1][2] + U[2][2]*U[2][2]);
            for (int r = 0; r < 3; r++) U[r][2] *= nrm;
        }

        float det = H[0][0]*(H[1][1]*H[2][2] - H[1][2]*H[2][1])
                  - H[0][1]*(H[1][0]*H[2][2] - H[1][2]*H[2][0])
                  + H[0][2]*(H[1][0]*H[2][1] - H[1][1]*H[2][0]);
        float sgn = (det < 0.0f) ? -1.0f : 1.0f;

        float R[3][3];
        for (int i = 0; i < 3; i++)
            for (int j = 0; j < 3; j++)
                R[i][j] = Vc[i][0]*U[j][0] + Vc[i][1]*U[j][1] + sgn * Vc[i][2]*U[j][2];

        for (int i = 0; i < 3; i++)
            for (int j = 0; j < 3; j++)
                out[b * 9 + i * 3 + j] = R[i][j];
        for (int i = 0; i < 3; i++)
            out[BQ * 9 + b * 3 + i] = mut[i] - (R[i][0]*mus[0] + R[i][1]*mus[1] + R[i][2]*mus[2]);
    }
}

extern "C" void kernel_launch(void* const* d_in, const int* in_sizes, int n_in,
                              void* d_out, int out_size, void* d_ws, size_t ws_size,
                              hipStream_t stream) {
    const float* src_emb = (const float*)d_in[0];
    const float* tgt_emb = (const float*)d_in[1];
    const float* src     = (const float*)d_in[2];
    const float* tgt     = (const float*)d_in[3];
    float* out = (float*)d_out;

    float* part = (float*)d_ws;                                            // 4 MiB
    __hip_bfloat16* Abf = (__hip_bfloat16*)((char*)d_ws + (4 << 20));       // 16 MiB
    __hip_bfloat16* Bbf = (__hip_bfloat16*)((char*)d_ws + (20 << 20));      // 16 MiB
    float* red = (float*)((char*)d_ws + (36 << 20));                        // 9 KiB

    dim3 gridT(NN / 256, DIM / 128, 2 * BQ);  // 8 x 4 x 16 = 512 blocks
    transpose_cast_kernel<<<gridT, 256, 0, stream>>>(src_emb, tgt_emb, Abf, Bbf);

    dim3 gridA(NN / 256, MM / 128, BQ);       // 8 x 16 x 8 = 1024 blocks
    attn_mfma_kernel<<<gridA, 256, 0, stream>>>(Abf, Bbf, tgt, part);

    dim3 gridR(16, BQ);                       // 128 blocks
    reduce1_kernel<<<gridR, 128, 0, stream>>>(part, src, tgt, red);

    procrustes_kernel<<<BQ, 64, 0, stream>>>(red, out);
}